// Round 4
// baseline (2050.526 us; speedup 1.0000x reference)
//
#include <hip/hip_runtime.h>
#include <hip/hip_bf16.h>
#include <math.h>

#define NBATCH 64
#define TSEQ   1000
#define DIN    257
#define HID    128
#define GATES  512   // 4*HID

typedef _Float16 h2 __attribute__((ext_vector_type(2)));

__device__ __forceinline__ float fast_sigmoid(float x) {
    return __builtin_amdgcn_rcpf(1.f + __expf(-x));
}
__device__ __forceinline__ float fast_tanh(float x) {
    const float ax = fabsf(x);
    const float e  = __expf(2.f * ax);            // large -> inf -> rcp -> 0 -> t=1 (safe)
    const float t  = 1.f - 2.f * __builtin_amdgcn_rcpf(e + 1.f);
    return copysignf(t, x);
}

// ---------------------------------------------------------------------------
// Generic tiled fp32 GEMM: C[M,Ncols] = act(A[M,K] @ W[Ncols,K]^T + b1 (+b2))
// (unchanged — isolate the lstm change this round)
// ---------------------------------------------------------------------------
template<int ACT>
__global__ __launch_bounds__(256) void gemm_bt(
    const float* __restrict__ A, const float* __restrict__ W,
    const float* __restrict__ b1, const float* __restrict__ b2,
    float* __restrict__ C, int M, int K, int Ncols)
{
    __shared__ float As[16][68];
    __shared__ float Ws[16][68];
    const int tid = threadIdx.x;
    const int tx  = tid & 15;
    const int ty  = tid >> 4;
    const int m0  = blockIdx.y * 64;
    const int n0  = blockIdx.x * 64;

    float acc[4][4];
#pragma unroll
    for (int i = 0; i < 4; ++i)
#pragma unroll
        for (int j = 0; j < 4; ++j) acc[i][j] = 0.f;

    for (int kc = 0; kc < K; kc += 16) {
        const int kk = tid & 15;
        const int r0 = tid >> 4;
#pragma unroll
        for (int rr = 0; rr < 64; rr += 16) {
            const int r  = r0 + rr;
            const int kg = kc + kk;
            float av = 0.f, wv = 0.f;
            if (kg < K) {
                av = A[(size_t)(m0 + r) * K + kg];
                const int wn = n0 + r;
                if (wn < Ncols) wv = W[(size_t)wn * K + kg];
            }
            As[kk][r] = av;
            Ws[kk][r] = wv;
        }
        __syncthreads();
#pragma unroll
        for (int k = 0; k < 16; ++k) {
            const float4 av4 = *(const float4*)&As[k][ty * 4];
            const float4 bv4 = *(const float4*)&Ws[k][tx * 4];
            const float a4[4] = {av4.x, av4.y, av4.z, av4.w};
            const float b4[4] = {bv4.x, bv4.y, bv4.z, bv4.w};
#pragma unroll
            for (int i = 0; i < 4; ++i)
#pragma unroll
                for (int j = 0; j < 4; ++j)
                    acc[i][j] += a4[i] * b4[j];
        }
        __syncthreads();
    }

#pragma unroll
    for (int i = 0; i < 4; ++i) {
        const int m = m0 + ty * 4 + i;
#pragma unroll
        for (int j = 0; j < 4; ++j) {
            const int col = n0 + tx * 4 + j;
            if (col < Ncols) {
                float v = acc[i][j] + b1[col] + (b2 ? b2[col] : 0.f);
                if (ACT == 1) v = 1.f / (1.f + __expf(-v));
                C[(size_t)m * Ncols + col] = v;
            }
        }
    }
}

// ---------------------------------------------------------------------------
// LSTM recurrence, readlane-broadcast version.
// One block per batch element (64 blocks), 256 threads; thread t owns gates
// t and t+256 (i/f in slot0, g/o in slot1 -> wave-uniform activation).
// h_t lives as packed f16x2 in ONE VGPR per wave (lane l = pair l); the
// recurrent dot uses v_readlane -> SGPR -> v_dot2_f32_f16, so the LDS pipe
// carries only the tiny per-step gate/h exchange.
// ---------------------------------------------------------------------------
__global__ __launch_bounds__(256, 1) void lstm_rec(
    const float* __restrict__ pre, const float* __restrict__ states_in,
    const float* __restrict__ Whh, float* __restrict__ hseq,
    float* __restrict__ states_out, int h_row0)
{
    const int n    = blockIdx.x;
    const int tid  = threadIdx.x;
    const int g0   = tid;          // i (tid<128) or f gate
    const int g1   = tid + 256;    // g (tid<128) or o gate
    const int lane = tid & 63;

    __shared__ float gates[GATES];
    __shared__ __align__(4) unsigned short h_u16[HID];   // h as f16 bits

    // Whh rows for both gates -> 128 packed f16x2 registers
    h2 w0[HID / 2], w1[HID / 2];
    {
        const float4* r0 = (const float4*)(Whh + (size_t)g0 * HID);
        const float4* r1 = (const float4*)(Whh + (size_t)g1 * HID);
#pragma unroll
        for (int k4 = 0; k4 < HID / 4; ++k4) {
            const float4 a = r0[k4];
            w0[2 * k4 + 0] = h2{(_Float16)a.x, (_Float16)a.y};
            w0[2 * k4 + 1] = h2{(_Float16)a.z, (_Float16)a.w};
            const float4 b = r1[k4];
            w1[2 * k4 + 0] = h2{(_Float16)b.x, (_Float16)b.y};
            w1[2 * k4 + 1] = h2{(_Float16)b.z, (_Float16)b.w};
        }
    }

    float c_r = 0.f;   // cell state for element tid (tid < 128 only)
    if (tid < HID) {
        const float hini = states_in[(size_t)(h_row0 + n) * HID + tid];
        c_r = states_in[(size_t)(h_row0 + 64 + n) * HID + tid];
        h_u16[tid] = __builtin_bit_cast(unsigned short, (_Float16)hini);
    }
    __syncthreads();

    // h vector for this wave: lane l holds f16 pair l (one dword)
    unsigned int vh = ((const unsigned int*)h_u16)[lane];

    const float* pre_n = pre + (size_t)n * TSEQ * GATES;
    float p0_cur = pre_n[g0],         p1_cur = pre_n[g1];
    float p0_nxt = pre_n[GATES + g0], p1_nxt = pre_n[GATES + g1];

    for (int t = 0; t < TSEQ; ++t) {
        const float p0 = p0_cur, p1 = p1_cur;
        p0_cur = p0_nxt; p1_cur = p1_nxt;
        if (t + 2 < TSEQ) {
            p0_nxt = pre_n[(size_t)(t + 2) * GATES + g0];
            p1_nxt = pre_n[(size_t)(t + 2) * GATES + g1];
        }

        // dot(h, Whh[g,:]) via readlane broadcast; 4 independent chains/gate
        float a0 = 0.f, a1 = 0.f, a2 = 0.f, a3 = 0.f;
        float b0 = 0.f, b1 = 0.f, b2 = 0.f, b3 = 0.f;
#pragma unroll
        for (int j = 0; j < 16; ++j) {
            const h2 u0 = __builtin_bit_cast(h2, __builtin_amdgcn_readlane((int)vh, 4 * j + 0));
            const h2 u1 = __builtin_bit_cast(h2, __builtin_amdgcn_readlane((int)vh, 4 * j + 1));
            const h2 u2 = __builtin_bit_cast(h2, __builtin_amdgcn_readlane((int)vh, 4 * j + 2));
            const h2 u3 = __builtin_bit_cast(h2, __builtin_amdgcn_readlane((int)vh, 4 * j + 3));
            a0 = __builtin_amdgcn_fdot2(w0[4 * j + 0], u0, a0, false);
            a1 = __builtin_amdgcn_fdot2(w0[4 * j + 1], u1, a1, false);
            a2 = __builtin_amdgcn_fdot2(w0[4 * j + 2], u2, a2, false);
            a3 = __builtin_amdgcn_fdot2(w0[4 * j + 3], u3, a3, false);
            b0 = __builtin_amdgcn_fdot2(w1[4 * j + 0], u0, b0, false);
            b1 = __builtin_amdgcn_fdot2(w1[4 * j + 1], u1, b1, false);
            b2 = __builtin_amdgcn_fdot2(w1[4 * j + 2], u2, b2, false);
            b3 = __builtin_amdgcn_fdot2(w1[4 * j + 3], u3, b3, false);
        }
        const float acc0 = p0 + ((a0 + a1) + (a2 + a3));
        const float acc1 = p1 + ((b0 + b1) + (b2 + b3));

        // slot0 (i/f): always sigmoid. slot1: tanh for waves 0-1 (g-gate),
        // sigmoid for waves 2-3 (o-gate) -> wave-uniform branch.
        const float act0 = fast_sigmoid(acc0);
        float act1;
        if ((tid >> 7) == 0) act1 = fast_tanh(acc1);
        else                 act1 = fast_sigmoid(acc1);
        gates[g0] = act0;
        gates[g1] = act1;
        __syncthreads();

        if (tid < HID) {
            const float i_ = gates[tid];
            const float f_ = gates[HID + tid];
            const float g_ = gates[2 * HID + tid];
            const float o_ = gates[3 * HID + tid];
            const float c  = f_ * c_r + i_ * g_;
            const float hh = o_ * fast_tanh(c);
            c_r = c;
            h_u16[tid] = __builtin_bit_cast(unsigned short, (_Float16)hh);
            hseq[((size_t)n * TSEQ + t) * HID + tid] = hh;
            if (t == TSEQ - 1) {
                states_out[(size_t)(h_row0 + n) * HID + tid]      = hh;
                states_out[(size_t)(h_row0 + 64 + n) * HID + tid] = c;
            }
        }
        __syncthreads();
        vh = ((const unsigned int*)h_u16)[lane];
    }
}

// ---------------------------------------------------------------------------
extern "C" void kernel_launch(void* const* d_in, const int* in_sizes, int n_in,
                              void* d_out, int out_size, void* d_ws, size_t ws_size,
                              hipStream_t stream)
{
    const float* x     = (const float*)d_in[0];
    const float* st_in = (const float*)d_in[1];
    const float* Wih1  = (const float*)d_in[2];
    const float* Whh1  = (const float*)d_in[3];
    const float* bih1  = (const float*)d_in[4];
    const float* bhh1  = (const float*)d_in[5];
    const float* Wih2  = (const float*)d_in[6];
    const float* Whh2  = (const float*)d_in[7];
    const float* bih2  = (const float*)d_in[8];
    const float* bhh2  = (const float*)d_in[9];
    const float* Wd    = (const float*)d_in[10];
    const float* bd    = (const float*)d_in[11];

    float* out_mask   = (float*)d_out;
    float* out_states = (float*)d_out + (size_t)NBATCH * TSEQ * DIN;

    const int M = NBATCH * TSEQ;
    float* bufA = (float*)d_ws;               // [M,512] pre1 / pre2
    float* bufB = bufA + (size_t)M * GATES;   // [M,128] h1seq / x2

    gemm_bt<0><<<dim3(GATES / 64, M / 64), 256, 0, stream>>>(
        x, Wih1, bih1, bhh1, bufA, M, DIN, GATES);

    lstm_rec<<<NBATCH, 256, 0, stream>>>(bufA, st_in, Whh1, bufB, out_states, 0);

    gemm_bt<0><<<dim3(GATES / 64, M / 64), 256, 0, stream>>>(
        bufB, Wih2, bih2, bhh2, bufA, M, HID, GATES);

    lstm_rec<<<NBATCH, 256, 0, stream>>>(bufA, st_in, Whh2, bufB, out_states, 128);

    gemm_bt<1><<<dim3((DIN + 63) / 64, M / 64), 256, 0, stream>>>(
        bufB, Wd, bd, nullptr, out_mask, M, HID, DIN);
}

// Round 5
// 1668.841 us; speedup vs baseline: 1.2287x; 1.2287x over previous
//
#include <hip/hip_runtime.h>
#include <hip/hip_bf16.h>
#include <math.h>

#define NBATCH 64
#define TSEQ   1000
#define DIN    257
#define HID    128
#define GATES  512   // 4*HID

typedef _Float16 h2 __attribute__((ext_vector_type(2)));

__device__ __forceinline__ float fast_sigmoid(float x) {
    return __builtin_amdgcn_rcpf(1.f + __expf(-x));
}
__device__ __forceinline__ float fast_tanh(float x) {
    const float ax = fabsf(x);
    const float e  = __expf(2.f * ax);            // large -> inf -> rcp -> 0 -> t=1 (safe)
    const float t  = 1.f - 2.f * __builtin_amdgcn_rcpf(e + 1.f);
    return copysignf(t, x);
}
// add partner lane's (lane^1) value: quad_perm [1,0,3,2] = dpp ctrl 0xB1
__device__ __forceinline__ float dpp_pair_add(float x) {
    const int xi = __builtin_bit_cast(int, x);
    const int yi = __builtin_amdgcn_update_dpp(0, xi, 0xB1, 0xF, 0xF, true);
    return x + __builtin_bit_cast(float, yi);
}

// ---------------------------------------------------------------------------
// Generic tiled fp32 GEMM: C[M,Ncols] = act(A[M,K] @ W[Ncols,K]^T + b1 (+b2))
// (unchanged — isolate the lstm change this round)
// ---------------------------------------------------------------------------
template<int ACT>
__global__ __launch_bounds__(256) void gemm_bt(
    const float* __restrict__ A, const float* __restrict__ W,
    const float* __restrict__ b1, const float* __restrict__ b2,
    float* __restrict__ C, int M, int K, int Ncols)
{
    __shared__ float As[16][68];
    __shared__ float Ws[16][68];
    const int tid = threadIdx.x;
    const int tx  = tid & 15;
    const int ty  = tid >> 4;
    const int m0  = blockIdx.y * 64;
    const int n0  = blockIdx.x * 64;

    float acc[4][4];
#pragma unroll
    for (int i = 0; i < 4; ++i)
#pragma unroll
        for (int j = 0; j < 4; ++j) acc[i][j] = 0.f;

    for (int kc = 0; kc < K; kc += 16) {
        const int kk = tid & 15;
        const int r0 = tid >> 4;
#pragma unroll
        for (int rr = 0; rr < 64; rr += 16) {
            const int r  = r0 + rr;
            const int kg = kc + kk;
            float av = 0.f, wv = 0.f;
            if (kg < K) {
                av = A[(size_t)(m0 + r) * K + kg];
                const int wn = n0 + r;
                if (wn < Ncols) wv = W[(size_t)wn * K + kg];
            }
            As[kk][r] = av;
            Ws[kk][r] = wv;
        }
        __syncthreads();
#pragma unroll
        for (int k = 0; k < 16; ++k) {
            const float4 av4 = *(const float4*)&As[k][ty * 4];
            const float4 bv4 = *(const float4*)&Ws[k][tx * 4];
            const float a4[4] = {av4.x, av4.y, av4.z, av4.w};
            const float b4[4] = {bv4.x, bv4.y, bv4.z, bv4.w};
#pragma unroll
            for (int i = 0; i < 4; ++i)
#pragma unroll
                for (int j = 0; j < 4; ++j)
                    acc[i][j] += a4[i] * b4[j];
        }
        __syncthreads();
    }

#pragma unroll
    for (int i = 0; i < 4; ++i) {
        const int m = m0 + ty * 4 + i;
#pragma unroll
        for (int j = 0; j < 4; ++j) {
            const int col = n0 + tx * 4 + j;
            if (col < Ncols) {
                float v = acc[i][j] + b1[col] + (b2 ? b2[col] : 0.f);
                if (ACT == 1) v = 1.f / (1.f + __expf(-v));
                C[(size_t)m * Ncols + col] = v;
            }
        }
    }
}

// ---------------------------------------------------------------------------
// LSTM recurrence, 4-gates-per-thread + K-half split.
// One block per batch element (64 blocks), 256 threads.
// Thread tid: hid j = tid>>1, K-half kh = tid&1; owns gates
// {j, j+128, j+256, j+384} = (i,f,g,o) for hid j -> update fully local.
// Partner lanes (l, l^1) hold the two K-halves; combined with a DPP
// quad_perm add (no LDS). h double-buffered in LDS -> ONE barrier/step,
// 8 ds_read_b128 per thread (32 wave-instrs/step vs 128 in the R2 version).
// ---------------------------------------------------------------------------
__global__ __launch_bounds__(256, 1) void lstm_rec(
    const float* __restrict__ pre, const float* __restrict__ states_in,
    const float* __restrict__ Whh, float* __restrict__ hseq,
    float* __restrict__ states_out, int h_row0)
{
    const int n   = blockIdx.x;
    const int tid = threadIdx.x;   // 0..255
    const int j   = tid >> 1;      // hid index 0..127
    const int kh  = tid & 1;       // K-half 0/1

    // Whh rows j, j+128, j+256, j+384; this thread's K-half -> 128 h2 regs
    h2 w[4][32];
#pragma unroll
    for (int a = 0; a < 4; ++a) {
        const float2* r = (const float2*)(Whh + (size_t)(j + a * HID) * HID + kh * 64);
#pragma unroll
        for (int m = 0; m < 32; ++m) {
            const float2 v = r[m];
            w[a][m] = h2{(_Float16)v.x, (_Float16)v.y};
        }
    }

    __shared__ __align__(16) unsigned short hbuf[2][HID];  // h_t as f16, double-buffered

    float c_r = states_in[(size_t)(h_row0 + 64 + n) * HID + j];  // both lanes of pair
    if (tid < HID) {
        const float h0 = states_in[(size_t)(h_row0 + n) * HID + tid];
        hbuf[0][tid] = __builtin_bit_cast(unsigned short, (_Float16)h0);
    }
    __syncthreads();

    const float* pre_n = pre + (size_t)n * TSEQ * GATES;
    float p0c = pre_n[j],            p1c = pre_n[j + 128];
    float p2c = pre_n[j + 256],      p3c = pre_n[j + 384];
    float p0n = pre_n[GATES + j],        p1n = pre_n[GATES + j + 128];
    float p2n = pre_n[GATES + j + 256],  p3n = pre_n[GATES + j + 384];

    int cur = 0;
    for (int t = 0; t < TSEQ; ++t) {
        const float p0 = p0c, p1 = p1c, p2 = p2c, p3 = p3c;
        p0c = p0n; p1c = p1n; p2c = p2n; p3c = p3n;
        if (t + 2 < TSEQ) {
            const float* pn = pre_n + (size_t)(t + 2) * GATES;
            p0n = pn[j];       p1n = pn[j + 128];
            p2n = pn[j + 256]; p3n = pn[j + 384];
        }

        // partial dots over this thread's K-half: 8 chunks x 4 gates x 4 dot2
        const uint4* hb = (const uint4*)&hbuf[cur][0];  // 16 uint4; half = 8
        float a0 = 0.f, a1 = 0.f, a2 = 0.f, a3 = 0.f;
#pragma unroll
        for (int c = 0; c < 8; ++c) {
            const uint4 hv = hb[kh * 8 + c];
            const h2 q0 = __builtin_bit_cast(h2, hv.x);
            const h2 q1 = __builtin_bit_cast(h2, hv.y);
            const h2 q2 = __builtin_bit_cast(h2, hv.z);
            const h2 q3 = __builtin_bit_cast(h2, hv.w);
            a0 = __builtin_amdgcn_fdot2(w[0][4 * c + 0], q0, a0, false);
            a1 = __builtin_amdgcn_fdot2(w[1][4 * c + 0], q0, a1, false);
            a2 = __builtin_amdgcn_fdot2(w[2][4 * c + 0], q0, a2, false);
            a3 = __builtin_amdgcn_fdot2(w[3][4 * c + 0], q0, a3, false);
            a0 = __builtin_amdgcn_fdot2(w[0][4 * c + 1], q1, a0, false);
            a1 = __builtin_amdgcn_fdot2(w[1][4 * c + 1], q1, a1, false);
            a2 = __builtin_amdgcn_fdot2(w[2][4 * c + 1], q1, a2, false);
            a3 = __builtin_amdgcn_fdot2(w[3][4 * c + 1], q1, a3, false);
            a0 = __builtin_amdgcn_fdot2(w[0][4 * c + 2], q2, a0, false);
            a1 = __builtin_amdgcn_fdot2(w[1][4 * c + 2], q2, a1, false);
            a2 = __builtin_amdgcn_fdot2(w[2][4 * c + 2], q2, a2, false);
            a3 = __builtin_amdgcn_fdot2(w[3][4 * c + 2], q2, a3, false);
            a0 = __builtin_amdgcn_fdot2(w[0][4 * c + 3], q3, a0, false);
            a1 = __builtin_amdgcn_fdot2(w[1][4 * c + 3], q3, a1, false);
            a2 = __builtin_amdgcn_fdot2(w[2][4 * c + 3], q3, a2, false);
            a3 = __builtin_amdgcn_fdot2(w[3][4 * c + 3], q3, a3, false);
        }

        // combine K-halves from partner lane (lane^1), add pre, activate
        const float gi = fast_sigmoid(dpp_pair_add(a0) + p0);
        const float gf = fast_sigmoid(dpp_pair_add(a1) + p1);
        const float gg = fast_tanh   (dpp_pair_add(a2) + p2);
        const float go = fast_sigmoid(dpp_pair_add(a3) + p3);

        const float cn = gf * c_r + gi * gg;
        const float hh = go * fast_tanh(cn);
        c_r = cn;

        // odd lane -> LDS next-buf; even lane -> global hseq (+ final states)
        if (kh) {
            hbuf[cur ^ 1][j] = __builtin_bit_cast(unsigned short, (_Float16)hh);
        } else {
            hseq[((size_t)n * TSEQ + t) * HID + j] = hh;
            if (t == TSEQ - 1) {
                states_out[(size_t)(h_row0 + n) * HID + j]      = hh;
                states_out[(size_t)(h_row0 + 64 + n) * HID + j] = cn;
            }
        }
        __syncthreads();
        cur ^= 1;
    }
}

// ---------------------------------------------------------------------------
extern "C" void kernel_launch(void* const* d_in, const int* in_sizes, int n_in,
                              void* d_out, int out_size, void* d_ws, size_t ws_size,
                              hipStream_t stream)
{
    const float* x     = (const float*)d_in[0];
    const float* st_in = (const float*)d_in[1];
    const float* Wih1  = (const float*)d_in[2];
    const float* Whh1  = (const float*)d_in[3];
    const float* bih1  = (const float*)d_in[4];
    const float* bhh1  = (const float*)d_in[5];
    const float* Wih2  = (const float*)d_in[6];
    const float* Whh2  = (const float*)d_in[7];
    const float* bih2  = (const float*)d_in[8];
    const float* bhh2  = (const float*)d_in[9];
    const float* Wd    = (const float*)d_in[10];
    const float* bd    = (const float*)d_in[11];

    float* out_mask   = (float*)d_out;
    float* out_states = (float*)d_out + (size_t)NBATCH * TSEQ * DIN;

    const int M = NBATCH * TSEQ;
    float* bufA = (float*)d_ws;               // [M,512] pre1 / pre2
    float* bufB = bufA + (size_t)M * GATES;   // [M,128] h1seq / x2

    gemm_bt<0><<<dim3(GATES / 64, M / 64), 256, 0, stream>>>(
        x, Wih1, bih1, bhh1, bufA, M, DIN, GATES);

    lstm_rec<<<NBATCH, 256, 0, stream>>>(bufA, st_in, Whh1, bufB, out_states, 0);

    gemm_bt<0><<<dim3(GATES / 64, M / 64), 256, 0, stream>>>(
        bufB, Wih2, bih2, bhh2, bufA, M, HID, GATES);

    lstm_rec<<<NBATCH, 256, 0, stream>>>(bufA, st_in, Whh2, bufB, out_states, 128);

    gemm_bt<1><<<dim3((DIN + 63) / 64, M / 64), 256, 0, stream>>>(
        bufB, Wd, bd, nullptr, out_mask, M, HID, DIN);
}

// Round 6
// 1655.912 us; speedup vs baseline: 1.2383x; 1.0078x over previous
//
#include <hip/hip_runtime.h>
#include <hip/hip_bf16.h>
#include <math.h>

#define NBATCH 64
#define TSEQ   1000
#define DIN    257
#define HID    128
#define GATES  512   // 4*HID

typedef _Float16 h2   __attribute__((ext_vector_type(2)));
typedef _Float16 half8 __attribute__((ext_vector_type(8)));
typedef float    f32x4 __attribute__((ext_vector_type(4)));

__device__ __forceinline__ float fast_sigmoid(float x) {
    return __builtin_amdgcn_rcpf(1.f + __expf(-x));
}
__device__ __forceinline__ float fast_tanh(float x) {
    const float ax = fabsf(x);
    const float e  = __expf(2.f * ax);
    const float t  = 1.f - 2.f * __builtin_amdgcn_rcpf(e + 1.f);
    return copysignf(t, x);
}
__device__ __forceinline__ float dpp_pair_add(float x) {
    const int xi = __builtin_bit_cast(int, x);
    const int yi = __builtin_amdgcn_update_dpp(0, xi, 0xB1, 0xF, 0xF, true);
    return x + __builtin_bit_cast(float, yi);
}

// ---------------------------------------------------------------------------
// f16 MFMA GEMM: C[M,Ncols] = act(A[M,K] @ W[Ncols,K]^T + b1 (+b2)), fp32 I/O.
// Block 256 thr = 4 waves, tile BM=128 x BN=64, BK=64, single-buffered LDS.
// Wave w: m-half (w>>1)*64, n-half (w&1)*32; 4x2 frags of 16x16 via
// mfma_f32_16x16x32_f16. LDS stride 88 f16 (176B): 16B-aligned rows, worst
// 2-way bank aliasing (free per m136).
// A-frag:  lane holds A[m=lane&15][k=(lane>>4)*8+j]  (K-contig 16B -> b128)
// W-frag:  lane holds W[n=lane&15][k=(lane>>4)*8+j]
// C/D   :  col=lane&15, row=(lane>>4)*4+reg          (verified m89/m91 layout)
// ---------------------------------------------------------------------------
#define BM 128
#define BN 64
#define BK 64
#define LDK 88

template<int ACT>
__global__ __launch_bounds__(256) void gemm_mfma(
    const float* __restrict__ A, const float* __restrict__ W,
    const float* __restrict__ b1, const float* __restrict__ b2,
    float* __restrict__ C, int M, int K, int Ncols)
{
    __shared__ _Float16 As[BM][LDK];
    __shared__ _Float16 Ws[BN][LDK];

    const int tid  = threadIdx.x;
    const int wave = tid >> 6;
    const int lane = tid & 63;
    const int r    = lane & 15;
    const int q    = lane >> 4;
    const int m0   = blockIdx.y * BM;
    const int n0   = blockIdx.x * BN;
    const int wm   = (wave >> 1) * 64;
    const int wn   = (wave & 1) * 32;

    f32x4 acc[4][2];
#pragma unroll
    for (int i = 0; i < 4; ++i)
#pragma unroll
        for (int j = 0; j < 2; ++j) acc[i][j] = f32x4{0.f, 0.f, 0.f, 0.f};

    const bool k4 = ((K & 3) == 0);   // uniform: fast float4 staging path

    for (int kc = 0; kc < K; kc += BK) {
        // ---- stage A: 128 rows x 64 k -> per thread 4 chunks of 8 f16
#pragma unroll
        for (int i = 0; i < 4; ++i) {
            const int chunk = tid + 256 * i;       // 0..1023
            const int row   = chunk >> 3;          // 0..127
            const int ko    = (chunk & 7) * 8;     // 0..56
            const int kg    = kc + ko;
            const float* src = A + (size_t)(m0 + row) * K + kg;
            _Float16 tmp[8];
            if (k4 && kg + 8 <= K) {
                const float4 u0 = *(const float4*)(src);
                const float4 u1 = *(const float4*)(src + 4);
                tmp[0] = (_Float16)u0.x; tmp[1] = (_Float16)u0.y;
                tmp[2] = (_Float16)u0.z; tmp[3] = (_Float16)u0.w;
                tmp[4] = (_Float16)u1.x; tmp[5] = (_Float16)u1.y;
                tmp[6] = (_Float16)u1.z; tmp[7] = (_Float16)u1.w;
            } else {
#pragma unroll
                for (int j = 0; j < 8; ++j)
                    tmp[j] = (kg + j < K) ? (_Float16)src[j] : (_Float16)0.f;
            }
            *(half8*)&As[row][ko] = *(half8*)tmp;
        }
        // ---- stage W: 64 rows x 64 k -> per thread 2 chunks of 8 f16
#pragma unroll
        for (int i = 0; i < 2; ++i) {
            const int chunk = tid + 256 * i;       // 0..511
            const int row   = chunk >> 3;          // 0..63
            const int ko    = (chunk & 7) * 8;
            const int kg    = kc + ko;
            const int wrow  = n0 + row;
            _Float16 tmp[8];
            if (wrow < Ncols) {
                const float* src = W + (size_t)wrow * K + kg;
                if (k4 && kg + 8 <= K) {
                    const float4 u0 = *(const float4*)(src);
                    const float4 u1 = *(const float4*)(src + 4);
                    tmp[0] = (_Float16)u0.x; tmp[1] = (_Float16)u0.y;
                    tmp[2] = (_Float16)u0.z; tmp[3] = (_Float16)u0.w;
                    tmp[4] = (_Float16)u1.x; tmp[5] = (_Float16)u1.y;
                    tmp[6] = (_Float16)u1.z; tmp[7] = (_Float16)u1.w;
                } else {
#pragma unroll
                    for (int j = 0; j < 8; ++j)
                        tmp[j] = (kg + j < K) ? (_Float16)src[j] : (_Float16)0.f;
                }
            } else {
#pragma unroll
                for (int j = 0; j < 8; ++j) tmp[j] = (_Float16)0.f;
            }
            *(half8*)&Ws[row][ko] = *(half8*)tmp;
        }
        __syncthreads();

        // ---- MFMA: two 32-k sub-chunks per buffer
#pragma unroll
        for (int s = 0; s < 2; ++s) {
            const int kb = s * 32 + q * 8;
            half8 af[4], wf[2];
#pragma unroll
            for (int i = 0; i < 4; ++i)
                af[i] = *(const half8*)&As[wm + i * 16 + r][kb];
#pragma unroll
            for (int j = 0; j < 2; ++j)
                wf[j] = *(const half8*)&Ws[wn + j * 16 + r][kb];
#pragma unroll
            for (int i = 0; i < 4; ++i)
#pragma unroll
                for (int j = 0; j < 2; ++j)
                    acc[i][j] = __builtin_amdgcn_mfma_f32_16x16x32_f16(
                        af[i], wf[j], acc[i][j], 0, 0, 0);
        }
        __syncthreads();
    }

    // ---- epilogue: row=(lane>>4)*4+reg, col=lane&15
#pragma unroll
    for (int i = 0; i < 4; ++i) {
#pragma unroll
        for (int j = 0; j < 2; ++j) {
            const int col = n0 + wn + j * 16 + r;
            if (col < Ncols) {
                const float bias = b1[col] + (b2 ? b2[col] : 0.f);
#pragma unroll
                for (int reg = 0; reg < 4; ++reg) {
                    const int row = m0 + wm + i * 16 + q * 4 + reg;
                    float v = acc[i][j][reg] + bias;
                    if (ACT == 1) v = fast_sigmoid(v);
                    C[(size_t)row * Ncols + col] = v;
                }
            }
        }
    }
}

// ---------------------------------------------------------------------------
// LSTM recurrence, 4-gates-per-thread + K-half split (unchanged from R5).
// ---------------------------------------------------------------------------
__global__ __launch_bounds__(256, 1) void lstm_rec(
    const float* __restrict__ pre, const float* __restrict__ states_in,
    const float* __restrict__ Whh, float* __restrict__ hseq,
    float* __restrict__ states_out, int h_row0)
{
    const int n   = blockIdx.x;
    const int tid = threadIdx.x;
    const int j   = tid >> 1;
    const int kh  = tid & 1;

    h2 w[4][32];
#pragma unroll
    for (int a = 0; a < 4; ++a) {
        const float2* rr = (const float2*)(Whh + (size_t)(j + a * HID) * HID + kh * 64);
#pragma unroll
        for (int m = 0; m < 32; ++m) {
            const float2 v = rr[m];
            w[a][m] = h2{(_Float16)v.x, (_Float16)v.y};
        }
    }

    __shared__ __align__(16) unsigned short hbuf[2][HID];

    float c_r = states_in[(size_t)(h_row0 + 64 + n) * HID + j];
    if (tid < HID) {
        const float h0 = states_in[(size_t)(h_row0 + n) * HID + tid];
        hbuf[0][tid] = __builtin_bit_cast(unsigned short, (_Float16)h0);
    }
    __syncthreads();

    const float* pre_n = pre + (size_t)n * TSEQ * GATES;
    float p0c = pre_n[j],            p1c = pre_n[j + 128];
    float p2c = pre_n[j + 256],      p3c = pre_n[j + 384];
    float p0n = pre_n[GATES + j],        p1n = pre_n[GATES + j + 128];
    float p2n = pre_n[GATES + j + 256],  p3n = pre_n[GATES + j + 384];

    int cur = 0;
    for (int t = 0; t < TSEQ; ++t) {
        const float p0 = p0c, p1 = p1c, p2 = p2c, p3 = p3c;
        p0c = p0n; p1c = p1n; p2c = p2n; p3c = p3n;
        if (t + 2 < TSEQ) {
            const float* pn = pre_n + (size_t)(t + 2) * GATES;
            p0n = pn[j];       p1n = pn[j + 128];
            p2n = pn[j + 256]; p3n = pn[j + 384];
        }

        const uint4* hb = (const uint4*)&hbuf[cur][0];
        float a0 = 0.f, a1 = 0.f, a2 = 0.f, a3 = 0.f;
#pragma unroll
        for (int c = 0; c < 8; ++c) {
            const uint4 hv = hb[kh * 8 + c];
            const h2 q0 = __builtin_bit_cast(h2, hv.x);
            const h2 q1 = __builtin_bit_cast(h2, hv.y);
            const h2 q2 = __builtin_bit_cast(h2, hv.z);
            const h2 q3 = __builtin_bit_cast(h2, hv.w);
            a0 = __builtin_amdgcn_fdot2(w[0][4 * c + 0], q0, a0, false);
            a1 = __builtin_amdgcn_fdot2(w[1][4 * c + 0], q0, a1, false);
            a2 = __builtin_amdgcn_fdot2(w[2][4 * c + 0], q0, a2, false);
            a3 = __builtin_amdgcn_fdot2(w[3][4 * c + 0], q0, a3, false);
            a0 = __builtin_amdgcn_fdot2(w[0][4 * c + 1], q1, a0, false);
            a1 = __builtin_amdgcn_fdot2(w[1][4 * c + 1], q1, a1, false);
            a2 = __builtin_amdgcn_fdot2(w[2][4 * c + 1], q1, a2, false);
            a3 = __builtin_amdgcn_fdot2(w[3][4 * c + 1], q1, a3, false);
            a0 = __builtin_amdgcn_fdot2(w[0][4 * c + 2], q2, a0, false);
            a1 = __builtin_amdgcn_fdot2(w[1][4 * c + 2], q2, a1, false);
            a2 = __builtin_amdgcn_fdot2(w[2][4 * c + 2], q2, a2, false);
            a3 = __builtin_amdgcn_fdot2(w[3][4 * c + 2], q2, a3, false);
            a0 = __builtin_amdgcn_fdot2(w[0][4 * c + 3], q3, a0, false);
            a1 = __builtin_amdgcn_fdot2(w[1][4 * c + 3], q3, a1, false);
            a2 = __builtin_amdgcn_fdot2(w[2][4 * c + 3], q3, a2, false);
            a3 = __builtin_amdgcn_fdot2(w[3][4 * c + 3], q3, a3, false);
        }

        const float gi = fast_sigmoid(dpp_pair_add(a0) + p0);
        const float gf = fast_sigmoid(dpp_pair_add(a1) + p1);
        const float gg = fast_tanh   (dpp_pair_add(a2) + p2);
        const float go = fast_sigmoid(dpp_pair_add(a3) + p3);

        const float cn = gf * c_r + gi * gg;
        const float hh = go * fast_tanh(cn);
        c_r = cn;

        if (kh) {
            hbuf[cur ^ 1][j] = __builtin_bit_cast(unsigned short, (_Float16)hh);
        } else {
            hseq[((size_t)n * TSEQ + t) * HID + j] = hh;
            if (t == TSEQ - 1) {
                states_out[(size_t)(h_row0 + n) * HID + j]      = hh;
                states_out[(size_t)(h_row0 + 64 + n) * HID + j] = cn;
            }
        }
        __syncthreads();
        cur ^= 1;
    }
}

// ---------------------------------------------------------------------------
extern "C" void kernel_launch(void* const* d_in, const int* in_sizes, int n_in,
                              void* d_out, int out_size, void* d_ws, size_t ws_size,
                              hipStream_t stream)
{
    const float* x     = (const float*)d_in[0];
    const float* st_in = (const float*)d_in[1];
    const float* Wih1  = (const float*)d_in[2];
    const float* Whh1  = (const float*)d_in[3];
    const float* bih1  = (const float*)d_in[4];
    const float* bhh1  = (const float*)d_in[5];
    const float* Wih2  = (const float*)d_in[6];
    const float* Whh2  = (const float*)d_in[7];
    const float* bih2  = (const float*)d_in[8];
    const float* bhh2  = (const float*)d_in[9];
    const float* Wd    = (const float*)d_in[10];
    const float* bd    = (const float*)d_in[11];

    float* out_mask   = (float*)d_out;
    float* out_states = (float*)d_out + (size_t)NBATCH * TSEQ * DIN;

    const int M = NBATCH * TSEQ;
    float* bufA = (float*)d_ws;               // [M,512] pre1 / pre2
    float* bufB = bufA + (size_t)M * GATES;   // [M,128] h1seq / x2

    // K1: pre1 = x @ Wih1^T + bih1 + bhh1   (M=64000, K=257, N=512)
    gemm_mfma<0><<<dim3(GATES / BN, M / BM), 256, 0, stream>>>(
        x, Wih1, bih1, bhh1, bufA, M, DIN, GATES);

    lstm_rec<<<NBATCH, 256, 0, stream>>>(bufA, st_in, Whh1, bufB, out_states, 0);

    // K3: pre2 = h1seq @ Wih2^T + bih2 + bhh2   (K=128)
    gemm_mfma<0><<<dim3(GATES / BN, M / BM), 256, 0, stream>>>(
        bufB, Wih2, bih2, bhh2, bufA, M, HID, GATES);

    lstm_rec<<<NBATCH, 256, 0, stream>>>(bufA, st_in, Whh2, bufB, out_states, 128);

    // K5: mask = sigmoid(x2 @ Wd^T + bd)   (N=257)
    gemm_mfma<1><<<dim3((DIN + BN - 1) / BN, M / BM), 256, 0, stream>>>(
        bufB, Wd, bd, nullptr, out_mask, M, HID, DIN);
}

// Round 7
// 1460.098 us; speedup vs baseline: 1.4044x; 1.1341x over previous
//
#include <hip/hip_runtime.h>
#include <hip/hip_bf16.h>
#include <math.h>

#define NBATCH 64
#define TSEQ   1000
#define DIN    257
#define HID    128
#define GATES  512   // 4*HID

typedef _Float16 h2    __attribute__((ext_vector_type(2)));
typedef _Float16 h4    __attribute__((ext_vector_type(4)));
typedef _Float16 half8 __attribute__((ext_vector_type(8)));
typedef float    f32x4 __attribute__((ext_vector_type(4)));

__device__ __forceinline__ float fast_sigmoid(float x) {
    return __builtin_amdgcn_rcpf(1.f + __expf(-x));
}
__device__ __forceinline__ float fast_tanh(float x) {
    const float ax = fabsf(x);
    const float e  = __expf(2.f * ax);
    const float t  = 1.f - 2.f * __builtin_amdgcn_rcpf(e + 1.f);
    return copysignf(t, x);
}
__device__ __forceinline__ float dpp_pair_add(float x) {
    const int xi = __builtin_bit_cast(int, x);
    const int yi = __builtin_amdgcn_update_dpp(0, xi, 0xB1, 0xF, 0xF, true);
    return x + __builtin_bit_cast(float, yi);
}

// ---------------------------------------------------------------------------
// f16 MFMA GEMM: C[M,Ncols] = act(A[M,K] @ W[Ncols,K]^T + b1 (+b2)), fp32 I/O.
// Tile BM=128 x BN=64, BK=64, 4 waves. Staging: 16 consecutive lanes cover one
// row contiguously (lane = float4 at (tid&15)*4) -> every cache line touched
// exactly once per instruction (R6's 8-floats/lane stride-32B mapping touched
// each line twice; K=257 scalar path touched each line 8x - that was the
// ~550us GEMM bug).
// A/W-frag: lane holds [m=lane&15][k=(lane>>4)*8+j]; C/D: col=lane&15,
// row=(lane>>4)*4+reg (m89/m91 layout).
// ---------------------------------------------------------------------------
#define BM 128
#define BN 64
#define BK 64
#define LDK 88

template<int ACT>
__global__ __launch_bounds__(256) void gemm_mfma(
    const float* __restrict__ A, const float* __restrict__ W,
    const float* __restrict__ b1, const float* __restrict__ b2,
    float* __restrict__ C, int M, int K, int Ncols)
{
    __shared__ _Float16 As[BM][LDK];
    __shared__ _Float16 Ws[BN][LDK];

    const int tid  = threadIdx.x;
    const int wave = tid >> 6;
    const int lane = tid & 63;
    const int r    = lane & 15;
    const int q    = lane >> 4;
    const int m0   = blockIdx.y * BM;
    const int n0   = blockIdx.x * BN;
    const int wm   = (wave >> 1) * 64;
    const int wn   = (wave & 1) * 32;

    const int r16 = tid >> 4;        // staging row sub-index 0..15
    const int c4  = (tid & 15) * 4;  // staging k-offset (floats)

    f32x4 acc[4][2];
#pragma unroll
    for (int i = 0; i < 4; ++i)
#pragma unroll
        for (int j = 0; j < 2; ++j) acc[i][j] = f32x4{0.f, 0.f, 0.f, 0.f};

    for (int kc = 0; kc < K; kc += BK) {
        const int kg = kc + c4;
        const bool vec_ok = (kg + 4 <= K);   // uniform within 16-lane row group

        // ---- stage A: 128 rows; 8 iters of 16 rows, contiguous per row
#pragma unroll
        for (int it = 0; it < 8; ++it) {
            const int row = it * 16 + r16;
            const float* src = A + (size_t)(m0 + row) * K + kg;
            _Float16 tmp[4];
            if (vec_ok) {
                const float4 u = *(const float4*)src;
                tmp[0] = (_Float16)u.x; tmp[1] = (_Float16)u.y;
                tmp[2] = (_Float16)u.z; tmp[3] = (_Float16)u.w;
            } else {
#pragma unroll
                for (int j = 0; j < 4; ++j)
                    tmp[j] = (kg + j < K) ? (_Float16)src[j] : (_Float16)0.f;
            }
            *(h4*)&As[row][c4] = *(h4*)tmp;
        }
        // ---- stage W: 64 rows; 4 iters of 16 rows
#pragma unroll
        for (int it = 0; it < 4; ++it) {
            const int row  = it * 16 + r16;
            const int wrow = n0 + row;
            _Float16 tmp[4] = {(_Float16)0.f, (_Float16)0.f, (_Float16)0.f, (_Float16)0.f};
            if (wrow < Ncols) {
                const float* src = W + (size_t)wrow * K + kg;
                if (vec_ok) {
                    const float4 u = *(const float4*)src;
                    tmp[0] = (_Float16)u.x; tmp[1] = (_Float16)u.y;
                    tmp[2] = (_Float16)u.z; tmp[3] = (_Float16)u.w;
                } else {
#pragma unroll
                    for (int j = 0; j < 4; ++j)
                        tmp[j] = (kg + j < K) ? (_Float16)src[j] : (_Float16)0.f;
                }
            }
            *(h4*)&Ws[row][c4] = *(h4*)tmp;
        }
        __syncthreads();

        // ---- MFMA: two 32-k sub-chunks per buffer
#pragma unroll
        for (int s = 0; s < 2; ++s) {
            const int kb = s * 32 + q * 8;
            half8 af[4], wf[2];
#pragma unroll
            for (int i = 0; i < 4; ++i)
                af[i] = *(const half8*)&As[wm + i * 16 + r][kb];
#pragma unroll
            for (int j = 0; j < 2; ++j)
                wf[j] = *(const half8*)&Ws[wn + j * 16 + r][kb];
#pragma unroll
            for (int i = 0; i < 4; ++i)
#pragma unroll
                for (int j = 0; j < 2; ++j)
                    acc[i][j] = __builtin_amdgcn_mfma_f32_16x16x32_f16(
                        af[i], wf[j], acc[i][j], 0, 0, 0);
        }
        __syncthreads();
    }

    // ---- epilogue: row=(lane>>4)*4+reg, col=lane&15
#pragma unroll
    for (int i = 0; i < 4; ++i) {
#pragma unroll
        for (int j = 0; j < 2; ++j) {
            const int col = n0 + wn + j * 16 + r;
            if (col < Ncols) {
                const float bias = b1[col] + (b2 ? b2[col] : 0.f);
#pragma unroll
                for (int reg = 0; reg < 4; ++reg) {
                    const int row = m0 + wm + i * 16 + q * 4 + reg;
                    float v = acc[i][j][reg] + bias;
                    if (ACT == 1) v = fast_sigmoid(v);
                    C[(size_t)row * Ncols + col] = v;
                }
            }
        }
    }
}

// ---------------------------------------------------------------------------
// LSTM recurrence, 4-gates-per-thread + K-half split (unchanged from R5).
// ---------------------------------------------------------------------------
__global__ __launch_bounds__(256, 1) void lstm_rec(
    const float* __restrict__ pre, const float* __restrict__ states_in,
    const float* __restrict__ Whh, float* __restrict__ hseq,
    float* __restrict__ states_out, int h_row0)
{
    const int n   = blockIdx.x;
    const int tid = threadIdx.x;
    const int j   = tid >> 1;
    const int kh  = tid & 1;

    h2 w[4][32];
#pragma unroll
    for (int a = 0; a < 4; ++a) {
        const float2* rr = (const float2*)(Whh + (size_t)(j + a * HID) * HID + kh * 64);
#pragma unroll
        for (int m = 0; m < 32; ++m) {
            const float2 v = rr[m];
            w[a][m] = h2{(_Float16)v.x, (_Float16)v.y};
        }
    }

    __shared__ __align__(16) unsigned short hbuf[2][HID];

    float c_r = states_in[(size_t)(h_row0 + 64 + n) * HID + j];
    if (tid < HID) {
        const float h0 = states_in[(size_t)(h_row0 + n) * HID + tid];
        hbuf[0][tid] = __builtin_bit_cast(unsigned short, (_Float16)h0);
    }
    __syncthreads();

    const float* pre_n = pre + (size_t)n * TSEQ * GATES;
    float p0c = pre_n[j],            p1c = pre_n[j + 128];
    float p2c = pre_n[j + 256],      p3c = pre_n[j + 384];
    float p0n = pre_n[GATES + j],        p1n = pre_n[GATES + j + 128];
    float p2n = pre_n[GATES + j + 256],  p3n = pre_n[GATES + j + 384];

    int cur = 0;
    for (int t = 0; t < TSEQ; ++t) {
        const float p0 = p0c, p1 = p1c, p2 = p2c, p3 = p3c;
        p0c = p0n; p1c = p1n; p2c = p2n; p3c = p3n;
        if (t + 2 < TSEQ) {
            const float* pn = pre_n + (size_t)(t + 2) * GATES;
            p0n = pn[j];       p1n = pn[j + 128];
            p2n = pn[j + 256]; p3n = pn[j + 384];
        }

        const uint4* hb = (const uint4*)&hbuf[cur][0];
        float a0 = 0.f, a1 = 0.f, a2 = 0.f, a3 = 0.f;
#pragma unroll
        for (int c = 0; c < 8; ++c) {
            const uint4 hv = hb[kh * 8 + c];
            const h2 q0 = __builtin_bit_cast(h2, hv.x);
            const h2 q1 = __builtin_bit_cast(h2, hv.y);
            const h2 q2 = __builtin_bit_cast(h2, hv.z);
            const h2 q3 = __builtin_bit_cast(h2, hv.w);
            a0 = __builtin_amdgcn_fdot2(w[0][4 * c + 0], q0, a0, false);
            a1 = __builtin_amdgcn_fdot2(w[1][4 * c + 0], q0, a1, false);
            a2 = __builtin_amdgcn_fdot2(w[2][4 * c + 0], q0, a2, false);
            a3 = __builtin_amdgcn_fdot2(w[3][4 * c + 0], q0, a3, false);
            a0 = __builtin_amdgcn_fdot2(w[0][4 * c + 1], q1, a0, false);
            a1 = __builtin_amdgcn_fdot2(w[1][4 * c + 1], q1, a1, false);
            a2 = __builtin_amdgcn_fdot2(w[2][4 * c + 1], q1, a2, false);
            a3 = __builtin_amdgcn_fdot2(w[3][4 * c + 1], q1, a3, false);
            a0 = __builtin_amdgcn_fdot2(w[0][4 * c + 2], q2, a0, false);
            a1 = __builtin_amdgcn_fdot2(w[1][4 * c + 2], q2, a1, false);
            a2 = __builtin_amdgcn_fdot2(w[2][4 * c + 2], q2, a2, false);
            a3 = __builtin_amdgcn_fdot2(w[3][4 * c + 2], q2, a3, false);
            a0 = __builtin_amdgcn_fdot2(w[0][4 * c + 3], q3, a0, false);
            a1 = __builtin_amdgcn_fdot2(w[1][4 * c + 3], q3, a1, false);
            a2 = __builtin_amdgcn_fdot2(w[2][4 * c + 3], q3, a2, false);
            a3 = __builtin_amdgcn_fdot2(w[3][4 * c + 3], q3, a3, false);
        }

        const float gi = fast_sigmoid(dpp_pair_add(a0) + p0);
        const float gf = fast_sigmoid(dpp_pair_add(a1) + p1);
        const float gg = fast_tanh   (dpp_pair_add(a2) + p2);
        const float go = fast_sigmoid(dpp_pair_add(a3) + p3);

        const float cn = gf * c_r + gi * gg;
        const float hh = go * fast_tanh(cn);
        c_r = cn;

        if (kh) {
            hbuf[cur ^ 1][j] = __builtin_bit_cast(unsigned short, (_Float16)hh);
        } else {
            hseq[((size_t)n * TSEQ + t) * HID + j] = hh;
            if (t == TSEQ - 1) {
                states_out[(size_t)(h_row0 + n) * HID + j]      = hh;
                states_out[(size_t)(h_row0 + 64 + n) * HID + j] = cn;
            }
        }
        __syncthreads();
        cur ^= 1;
    }
}

// ---------------------------------------------------------------------------
extern "C" void kernel_launch(void* const* d_in, const int* in_sizes, int n_in,
                              void* d_out, int out_size, void* d_ws, size_t ws_size,
                              hipStream_t stream)
{
    const float* x     = (const float*)d_in[0];
    const float* st_in = (const float*)d_in[1];
    const float* Wih1  = (const float*)d_in[2];
    const float* Whh1  = (const float*)d_in[3];
    const float* bih1  = (const float*)d_in[4];
    const float* bhh1  = (const float*)d_in[5];
    const float* Wih2  = (const float*)d_in[6];
    const float* Whh2  = (const float*)d_in[7];
    const float* bih2  = (const float*)d_in[8];
    const float* bhh2  = (const float*)d_in[9];
    const float* Wd    = (const float*)d_in[10];
    const float* bd    = (const float*)d_in[11];

    float* out_mask   = (float*)d_out;
    float* out_states = (float*)d_out + (size_t)NBATCH * TSEQ * DIN;

    const int M = NBATCH * TSEQ;
    float* bufA = (float*)d_ws;               // [M,512] pre1 / pre2
    float* bufB = bufA + (size_t)M * GATES;   // [M,128] h1seq / x2

    // K1: pre1 = x @ Wih1^T + bih1 + bhh1   (M=64000, K=257, N=512)
    gemm_mfma<0><<<dim3(GATES / BN, M / BM), 256, 0, stream>>>(
        x, Wih1, bih1, bhh1, bufA, M, DIN, GATES);

    lstm_rec<<<NBATCH, 256, 0, stream>>>(bufA, st_in, Whh1, bufB, out_states, 0);

    // K3: pre2 = h1seq @ Wih2^T + bih2 + bhh2   (K=128)
    gemm_mfma<0><<<dim3(GATES / BN, M / BM), 256, 0, stream>>>(
        bufB, Wih2, bih2, bhh2, bufA, M, HID, GATES);

    lstm_rec<<<NBATCH, 256, 0, stream>>>(bufA, st_in, Whh2, bufB, out_states, 128);

    // K5: mask = sigmoid(x2 @ Wd^T + bd)   (N=257)
    gemm_mfma<1><<<dim3((DIN + BN - 1) / BN, M / BM), 256, 0, stream>>>(
        bufB, Wd, bd, nullptr, out_mask, M, HID, DIN);
}